// Round 2
// baseline (177.719 us; speedup 1.0000x reference)
//
#include <hip/hip_runtime.h>
#include <float.h>

// VQ-VAE vector quantizer, MI355X fp32 vector-ALU version.
// z: [32,64,32,32] f32, codebook: [1024,64] f32
// out (f32 flat): z_q [2097152] | loss [1] | indices-as-float [32768]
//
// Numerics contract: the checker's reference is numpy fp32 with
//   d = sum(z^2,axis=1,keepdims) + sum(e^2,axis=1) - 2*(z @ e.T)
// The ||z||^2 term quantizes scores to ulp(~64) ~ 7.6e-6, creating exact
// rounded ties that argmin resolves as first-index. We replicate that
// rounding bitwise: numpy pairwise-sum tree for the norms (rounded squares,
// fp contract OFF), sequential fma chain for the dot (BLAS microkernel
// order), score = fl(fl(zz+ee) - 2*dot).

#define DIM       64
#define N_EMB     1024
#define LOSS_OFF  2097152
#define IDX_OFF   2097153
// loss = 1.25 * sum / 2^21  (exact fp32 constant)
#define LOSS_SCALE 5.9604644775390625e-07f

// numpy pairwise_sum over 64 elements of a^2, exact tree:
// r[j] = ((((((sq[j]+sq[j+8])+sq[j+16])+...)+sq[j+56]   (j=0..7)
// res  = ((r0+r1)+(r2+r3)) + ((r4+r5)+(r6+r7))
__device__ __forceinline__ float np_sumsq64(const float* a) {
    #pragma clang fp contract(off)
    float r[8];
    #pragma unroll
    for (int j = 0; j < 8; ++j) {
        float s = a[j] * a[j];
        #pragma unroll
        for (int m = 1; m < 8; ++m) {
            float p = a[j + 8 * m] * a[j + 8 * m];
            s = s + p;
        }
        r[j] = s;
    }
    return ((r[0] + r[1]) + (r[2] + r[3])) + ((r[4] + r[5]) + (r[6] + r[7]));
}

// grid 512 blocks x 512 threads; block = 64 pixels, 8 waves x 128-code slices
__global__ __launch_bounds__(512, 2)
void vq_main(const float* __restrict__ z, const float* __restrict__ cb,
             float* __restrict__ out, float* __restrict__ ws_partial) {
    __shared__ float esq[N_EMB];
    __shared__ float cand_val[8 * 64];
    __shared__ int   cand_idx[8 * 64];
    __shared__ int   fidx[64];
    __shared__ float lred[8];

    const int tid  = threadIdx.x;
    const int lane = tid & 63;
    const int wave = __builtin_amdgcn_readfirstlane(tid >> 6);  // uniform wave id
    const int n0   = blockIdx.x * 64;          // first pixel of this block
    const int b    = n0 >> 10;                 // batch (1024 pixels per image)
    const int hw0  = n0 & 1023;
    const size_t zbase = (size_t)b * 65536 + (size_t)hw0;  // z[b][c][hw]

    // ---- 1) codebook squared norms -> LDS, numpy tree (2 codes/thread) ----
    {
        #pragma clang fp contract(off)
        for (int t = 0; t < 2; ++t) {
            const int k = tid * 2 + t;
            float a[DIM];
            const float4* row = (const float4*)(cb + (size_t)k * DIM);
            #pragma unroll
            for (int j = 0; j < 16; ++j) ((float4*)a)[j] = row[j];
            esq[k] = np_sumsq64(a);
        }
    }

    // ---- 2) this lane's pixel vector into 64 VGPRs + its numpy-tree norm ----
    float vz[DIM];
    #pragma unroll
    for (int c = 0; c < DIM; ++c)
        vz[c] = z[zbase + (size_t)c * 1024 + lane];   // coalesced across lanes
    const float zz = np_sumsq64(vz);

    __syncthreads();

    // ---- 3) argmin of fl(fl(zz+ee_k) - 2*dot_k) over this wave's slice ----
    float best = FLT_MAX;
    int   bidx = 0;
    const int kbase = wave * 128;
    for (int k = kbase; k < kbase + 128; k += 2) {   // k uniform -> s_load rows
        const float* e0 = cb + (size_t)k * DIM;
        const float* e1 = e0 + DIM;
        float d0 = 0.f, d1 = 0.f;                     // BLAS-style fma chains
        #pragma unroll
        for (int c = 0; c < DIM; ++c) {
            d0 = __builtin_fmaf(e0[c], vz[c], d0);
            d1 = __builtin_fmaf(e1[c], vz[c], d1);
        }
        float s0, s1;
        {
            #pragma clang fp contract(off)
            float p0 = zz + esq[k];
            float p1 = zz + esq[k + 1];
            s0 = p0 - 2.0f * d0;
            s1 = p1 - 2.0f * d1;
        }
        if (s0 < best) { best = s0; bidx = k; }       // ascending k => first-min
        if (s1 < best) { best = s1; bidx = k + 1; }
    }
    cand_val[wave * 64 + lane] = best;
    cand_idx[wave * 64 + lane] = bidx;
    __syncthreads();

    // ---- 4) reduce 8 wave-candidates per pixel; write indices output ----
    if (tid < 64) {
        float bv = cand_val[tid];
        int   bi = cand_idx[tid];
        #pragma unroll
        for (int w = 1; w < 8; ++w) {
            float v = cand_val[w * 64 + tid];
            int   i = cand_idx[w * 64 + tid];
            if (v < bv || (v == bv && i < bi)) { bv = v; bi = i; }
        }
        fidx[tid] = bi;
        out[IDX_OFF + n0 + tid] = (float)bi;
    }
    __syncthreads();

    // ---- 5) z_q scatter-write (coalesced by hw) + loss partial ----
    const int px  = tid & 63;
    const int cg  = tid >> 6;   // 0..7 -> channels cg*8 .. cg*8+7
    const int mi  = fidx[px];
    float lacc = 0.f;
    #pragma unroll
    for (int i = 0; i < 8; ++i) {
        const int c = cg * 8 + i;
        float q  = cb[mi * DIM + c];                    // L2-resident gather
        size_t go = zbase + (size_t)c * 1024 + px;
        float zv = z[go];                               // coalesced
        float d  = q - zv;
        lacc = __builtin_fmaf(d, d, lacc);
        out[go] = q;                                    // coalesced
    }
    #pragma unroll
    for (int off = 32; off > 0; off >>= 1)
        lacc += __shfl_down(lacc, off, 64);
    if (lane == 0) lred[wave] = lacc;
    __syncthreads();
    if (tid == 0) {
        float t = 0.f;
        #pragma unroll
        for (int w = 0; w < 8; ++w) t += lred[w];
        ws_partial[blockIdx.x] = t;
    }
}

// single block, 512 threads: sum the 512 block partials -> loss
__global__ __launch_bounds__(512)
void vq_loss_finalize(const float* __restrict__ ws_partial, float* __restrict__ out) {
    __shared__ float red[8];
    const int tid = threadIdx.x;
    float v = ws_partial[tid];
    #pragma unroll
    for (int off = 32; off > 0; off >>= 1)
        v += __shfl_down(v, off, 64);
    const int lane = tid & 63, wave = tid >> 6;
    if (lane == 0) red[wave] = v;
    __syncthreads();
    if (tid == 0) {
        float t = 0.f;
        #pragma unroll
        for (int w = 0; w < 8; ++w) t += red[w];
        out[LOSS_OFF] = t * LOSS_SCALE;
    }
}

extern "C" void kernel_launch(void* const* d_in, const int* in_sizes, int n_in,
                              void* d_out, int out_size, void* d_ws, size_t ws_size,
                              hipStream_t stream) {
    const float* z  = (const float*)d_in[0];   // 2097152 f32
    const float* cb = (const float*)d_in[1];   // 65536 f32
    float* out = (float*)d_out;
    float* ws  = (float*)d_ws;                 // needs 512 * 4 B

    vq_main<<<512, 512, 0, stream>>>(z, cb, out, ws);
    vq_loss_finalize<<<1, 512, 0, stream>>>(ws, out);
}

// Round 3
// 127.862 us; speedup vs baseline: 1.3899x; 1.3899x over previous
//
#include <hip/hip_runtime.h>
#include <float.h>

// VQ-VAE vector quantizer, MI355X fp32 vector-ALU version, round 3.
// z: [32,64,32,32] f32, codebook: [1024,64] f32
// out (f32 flat): z_q [2097152] | loss [1] | indices-as-float [32768]
//
// Numerics contract (DO NOT CHANGE — bitwise-matches the numpy fp32 ref):
//  - code/pixel norms: numpy pairwise-sum tree over 64 rounded squares,
//    fp contract OFF
//  - dot: single k-ordered fma chain per (pixel, code)  (== OpenBLAS sgemm
//    microkernel accumulation)
//  - score: fl(fl(zz+ee) - 2*dot), strict-< first-min, ascending k,
//    wave w owns codes [w*128, w*128+128)
//
// Round-3 perf change: 2 pixels per lane (4 independent fma chains per
// 2-code step) so each 512 B SGPR codebook row-pair feeds 256 fmas instead
// of 128 — covers scalar-cache chunk-load latency that capped round 2 at
// VALUBusy=52%.

#define DIM       64
#define N_EMB     1024
#define LOSS_OFF  2097152
#define IDX_OFF   2097153
// loss = 1.25 * sum / 2^21  (exact fp32 constant)
#define LOSS_SCALE 5.9604644775390625e-07f

// numpy pairwise_sum over 64 elements of a^2, exact tree.
__device__ __forceinline__ float np_sumsq64(const float* a) {
    #pragma clang fp contract(off)
    float r[8];
    #pragma unroll
    for (int j = 0; j < 8; ++j) {
        float s = a[j] * a[j];
        #pragma unroll
        for (int m = 1; m < 8; ++m) {
            float p = a[j + 8 * m] * a[j + 8 * m];
            s = s + p;
        }
        r[j] = s;
    }
    return ((r[0] + r[1]) + (r[2] + r[3])) + ((r[4] + r[5]) + (r[6] + r[7]));
}

// grid 256 blocks x 512 threads; block = 128 pixels (2/lane),
// 8 waves x 128-code slices
__global__ __launch_bounds__(512, 2)
void vq_main(const float* __restrict__ z, const float* __restrict__ cb,
             float* __restrict__ out, float* __restrict__ ws_partial) {
    __shared__ float esq[N_EMB];
    __shared__ float cand_val[8 * 128];
    __shared__ int   cand_idx[8 * 128];
    __shared__ int   fidx[128];
    __shared__ float lred[8];

    const int tid  = threadIdx.x;
    const int lane = tid & 63;
    const int wave = __builtin_amdgcn_readfirstlane(tid >> 6);  // uniform
    const int n0   = blockIdx.x * 128;         // first pixel of this block
    const int b    = n0 >> 10;                 // batch image (1024 px each)
    const int hw0  = n0 & 1023;
    const size_t zbase = (size_t)b * 65536 + (size_t)hw0;  // z[b][c][hw]

    // ---- 1) codebook squared norms -> LDS, numpy tree (2 codes/thread) ----
    {
        #pragma clang fp contract(off)
        for (int t = 0; t < 2; ++t) {
            const int k = tid * 2 + t;
            float a[DIM];
            const float4* row = (const float4*)(cb + (size_t)k * DIM);
            #pragma unroll
            for (int j = 0; j < 16; ++j) ((float4*)a)[j] = row[j];
            esq[k] = np_sumsq64(a);
        }
    }

    // ---- 2) two pixel vectors per lane (px0=lane, px1=lane+64) ----
    float vz0[DIM], vz1[DIM];
    #pragma unroll
    for (int c = 0; c < DIM; ++c) {
        vz0[c] = z[zbase + (size_t)c * 1024 + lane];        // coalesced
        vz1[c] = z[zbase + (size_t)c * 1024 + lane + 64];   // coalesced
    }
    const float zz0 = np_sumsq64(vz0);
    const float zz1 = np_sumsq64(vz1);

    __syncthreads();

    // ---- 3) argmin over this wave's 128-code slice, 4 fma chains ----
    float best0 = FLT_MAX, best1 = FLT_MAX;
    int   bidx0 = 0,       bidx1 = 0;
    const int kbase = wave * 128;
    for (int k = kbase; k < kbase + 128; k += 2) {   // uniform k -> s_load rows
        const float* e0 = cb + (size_t)k * DIM;
        const float* e1 = e0 + DIM;
        float d00 = 0.f, d01 = 0.f, d10 = 0.f, d11 = 0.f;
        #pragma unroll
        for (int c = 0; c < DIM; ++c) {
            const float a0 = e0[c];
            const float a1 = e1[c];
            d00 = __builtin_fmaf(a0, vz0[c], d00);   // code k,   px0
            d01 = __builtin_fmaf(a0, vz1[c], d01);   // code k,   px1
            d10 = __builtin_fmaf(a1, vz0[c], d10);   // code k+1, px0
            d11 = __builtin_fmaf(a1, vz1[c], d11);   // code k+1, px1
        }
        float s00, s01, s10, s11;
        {
            #pragma clang fp contract(off)
            const float p0 = zz0 + esq[k];
            const float p1 = zz1 + esq[k];
            const float q0 = zz0 + esq[k + 1];
            const float q1 = zz1 + esq[k + 1];
            s00 = p0 - 2.0f * d00;
            s01 = p1 - 2.0f * d01;
            s10 = q0 - 2.0f * d10;
            s11 = q1 - 2.0f * d11;
        }
        if (s00 < best0) { best0 = s00; bidx0 = k; }      // ascending k =>
        if (s10 < best0) { best0 = s10; bidx0 = k + 1; }  // first-min kept
        if (s01 < best1) { best1 = s01; bidx1 = k; }
        if (s11 < best1) { best1 = s11; bidx1 = k + 1; }
    }
    cand_val[wave * 128 + lane]      = best0;
    cand_idx[wave * 128 + lane]      = bidx0;
    cand_val[wave * 128 + 64 + lane] = best1;
    cand_idx[wave * 128 + 64 + lane] = bidx1;
    __syncthreads();

    // ---- 4) reduce 8 wave-candidates per pixel; write indices output ----
    if (tid < 128) {
        float bv = cand_val[tid];
        int   bi = cand_idx[tid];
        #pragma unroll
        for (int w = 1; w < 8; ++w) {
            float v = cand_val[w * 128 + tid];
            int   i = cand_idx[w * 128 + tid];
            if (v < bv || (v == bv && i < bi)) { bv = v; bi = i; }
        }
        fidx[tid] = bi;
        out[IDX_OFF + n0 + tid] = (float)bi;
    }
    __syncthreads();

    // ---- 5) z_q write (coalesced by hw) + loss partial ----
    const int px = tid & 127;
    const int cg = tid >> 7;      // 0..3 -> channels cg*16 .. cg*16+15
    const int mi = fidx[px];
    float lacc = 0.f;
    #pragma unroll
    for (int i = 0; i < 16; ++i) {
        const int c = cg * 16 + i;
        float q  = cb[mi * DIM + c];                    // L2-resident gather
        size_t go = zbase + (size_t)c * 1024 + px;
        float zv = z[go];                               // coalesced
        float d  = q - zv;
        lacc = __builtin_fmaf(d, d, lacc);
        out[go] = q;                                    // coalesced
    }
    #pragma unroll
    for (int off = 32; off > 0; off >>= 1)
        lacc += __shfl_down(lacc, off, 64);
    if (lane == 0) lred[wave] = lacc;
    __syncthreads();
    if (tid == 0) {
        float t = 0.f;
        #pragma unroll
        for (int w = 0; w < 8; ++w) t += lred[w];
        ws_partial[blockIdx.x] = t;
    }
}

// single block, 256 threads: sum the 256 block partials -> loss
__global__ __launch_bounds__(256)
void vq_loss_finalize(const float* __restrict__ ws_partial, float* __restrict__ out) {
    __shared__ float red[4];
    const int tid = threadIdx.x;
    float v = ws_partial[tid];
    #pragma unroll
    for (int off = 32; off > 0; off >>= 1)
        v += __shfl_down(v, off, 64);
    const int lane = tid & 63, wave = tid >> 6;
    if (lane == 0) red[wave] = v;
    __syncthreads();
    if (tid == 0) {
        float t = 0.f;
        #pragma unroll
        for (int w = 0; w < 4; ++w) t += red[w];
        out[LOSS_OFF] = t * LOSS_SCALE;
    }
}

extern "C" void kernel_launch(void* const* d_in, const int* in_sizes, int n_in,
                              void* d_out, int out_size, void* d_ws, size_t ws_size,
                              hipStream_t stream) {
    const float* z  = (const float*)d_in[0];   // 2097152 f32
    const float* cb = (const float*)d_in[1];   // 65536 f32
    float* out = (float*)d_out;
    float* ws  = (float*)d_ws;                 // needs 256 * 4 B

    vq_main<<<256, 512, 0, stream>>>(z, cb, out, ws);
    vq_loss_finalize<<<1, 256, 0, stream>>>(ws, out);
}